// Round 11
// baseline (724.383 us; speedup 1.0000x reference)
//
#include <hip/hip_runtime.h>
#include <stdint.h>

#define BB   16384
#define SS   50
#define DD   64
#define NH1  80
#define NB   16          // batches per workgroup
#define MT   50          // 16-row M-tiles per WG (NB*SS/16)
#define NWAVE 8          // 512-thread blocks

// workspace layout (shorts)
#define WS_UVW_SHORTS   (30*64*8)                 // 15360 (30 frags, GEMM1)
#define WS_W2F_OFF      WS_UVW_SHORTS             // W2 16x16x16 frags
#define WS_W2F_SHORTS   (3*1280)                  // 3840 shorts = 7680 B
#define WS_QP_BYTE_OFF  (2*(WS_UVW_SHORTS+WS_W2F_SHORTS))  // 38400 B
#define WS_QP_FLOATS    (SS*DD)                   // 3200 floats

typedef short bf16x8 __attribute__((ext_vector_type(8)));
typedef short bf16x4 __attribute__((ext_vector_type(4)));
typedef float f32x4  __attribute__((ext_vector_type(4)));
typedef int   i32x4  __attribute__((ext_vector_type(4)));

// software RTNE f32->bf16 (prep/weights — exact)
__device__ inline short f2bf(float x) {
    union { float f; uint32_t u; } v; v.f = x;
    uint32_t r = (v.u + 0x7FFFu + ((v.u >> 16) & 1u)) >> 16;
    return (short)r;
}
// round-half-away f32->bf16 pack (no systematic bias; R4 lesson: HW cvt_pk is biased)
__device__ inline uint32_t f2bf2(float lo, float hi) {
    uint32_t ua = __builtin_bit_cast(uint32_t, lo) + 0x8000u;
    uint32_t ub = __builtin_bit_cast(uint32_t, hi) + 0x8000u;
    return __byte_perm(ua, ub, 0x7632);
}
__device__ inline float fexp(float x)  { return __builtin_amdgcn_exp2f(x * 1.44269504f); }
__device__ inline float fsig(float x)  { return __builtin_amdgcn_rcpf(1.f + fexp(-x)); }

#if defined(__has_builtin)
#if __has_builtin(__builtin_amdgcn_mfma_f32_16x16x16bf16_1k)
#define HAVE_MFMA16 1
#endif
#endif

// 16x16x16 bf16 MFMA: A/B = 4 bf16/lane (row=l&15, k=4*(l>>4)+j), C same 16x16 layout
__device__ inline f32x4 mfma16(bf16x4 a, bf16x4 b, f32x4 c) {
#ifdef HAVE_MFMA16
    return __builtin_amdgcn_mfma_f32_16x16x16bf16_1k(a, b, c, 0, 0, 0);
#else
    asm volatile("s_nop 1\n\tv_mfma_f32_16x16x16_bf16 %0, %1, %2, %0"
                 : "+v"(c) : "v"(a), "v"(b));
    return c;
#endif
}
__device__ inline void mfma16_hazard_fence() {
#ifndef HAVE_MFMA16
    asm volatile("s_nop 7\n\ts_nop 7" ::: );
#endif
}

// ---------------- pre-kernel: build weight images once ----------------
__global__ __launch_bounds__(256) void i2i_prep(
    const float* __restrict__ pos, const float* __restrict__ Wq,
    const float* __restrict__ bq,  const float* __restrict__ W1,
    const float* __restrict__ W2,  short* __restrict__ ws_s,
    float* __restrict__ qp)
{
    int gid = blockIdx.x * 256 + threadIdx.x;
    if (gid < 1920) {
        // UVW fragments, frag f = t*6+ks (works as A or B side, layout-symmetric)
        int frag = gid >> 6, lane = gid & 63;
        int t = frag / 6, ks = frag % 6;
        int i16 = lane & 15, g = lane >> 4;
        int h = 16*t + i16;
        int kbase = 32*ks + 8*g;
        short tmp[8];
        #pragma unroll
        for (int j = 0; j < 8; ++j) {
            int k = kbase + j;
            float v;
            if (k < 64)       v = W1[k*NH1 + h] + W1[(128+k)*NH1 + h];   // U = W1a+W1c
            else if (k < 128) v = W1[k*NH1 + h] - W1[(k+64)*NH1 + h];    // V = W1b-W1c
            else              v = W1[(k+64)*NH1 + h];                    // W = W1d
            tmp[j] = f2bf(v);
        }
        *(bf16x8*)&ws_s[gid*8] = *(bf16x8*)tmp;
    } else if (gid < 1920 + 960) {
        // W2 frags for 16x16x16: B[k=16t+4g+j][col=i16+16t2], zero col>=40.
        // layout per t2 (1280 shorts): [t01: lane*8][t23: +512, lane*8][t4: +1024, lane*4]
        int idx = gid - 1920;
        int t2 = idx / 320, rem = idx % 320;
        int t = rem >> 6, lane = rem & 63;
        int i16 = lane & 15, g = lane >> 4;
        int col = i16 + 16*t2;
        short tmp[4];
        #pragma unroll
        for (int j = 0; j < 4; ++j) {
            int k = 16*t + 4*g + j;
            tmp[j] = (col < 40) ? f2bf(W2[k*40 + col]) : (short)0;
        }
        int dst = WS_W2F_OFF + t2*1280 +
                  ((t < 4) ? ((t>>1)*512 + lane*8 + (t&1)*4) : (1024 + lane*4));
        *(bf16x4*)&ws_s[dst] = *(bf16x4*)tmp;
    } else if (gid < 1920 + 960 + WS_QP_FLOATS) {
        int idx = gid - 1920 - 960;
        int s = idx >> 6, d = idx & 63;
        float acc = bq[d];
        #pragma unroll
        for (int p = 0; p < 4; ++p) acc += pos[s*4 + p] * Wq[(64+p)*64 + d];
        qp[idx] = acc;
    }
}

// ---------------- main kernel ----------------
__global__ __launch_bounds__(512, 6) void i2i_kernel(
    const float* __restrict__ target, const float* __restrict__ seq,
    const int*   __restrict__ mask,   const float* __restrict__ Wq,
    const float* __restrict__ alpha,  const float* __restrict__ b1,
    const float* __restrict__ b2,     const float* __restrict__ W3,
    const float* __restrict__ b3,     const short* __restrict__ ws_s,
    const float* __restrict__ qp,     float* __restrict__ out)
{
    // LDS: 30720 + 7680 + 4352 + 3328 = 46080 B -> 3 blocks/CU at VGPR<=85
    __shared__ short uvw[30*512];        // GEMM1 weight frags
    __shared__ short w2f[WS_W2F_SHORTS]; // GEMM2 weight frags (16x16x16)
    __shared__ float qtLDS[NB][68];      // target @ Wq[:64]
    __shared__ float scores[NB][52];     // raw scores, then softmax p

    const int tid  = threadIdx.x;
    const int wg   = blockIdx.x;
    const int b0   = wg * NB;
    const int lane = tid & 63;
    const int wv   = tid >> 6;

    // ---------------- phase 0: LDS build (linear copies) ----------------
    #pragma unroll
    for (int o = 0; o < 4; ++o) {        // uvw: 1920 int4
        int idx = tid + o*512;
        if (idx < 1920) ((i32x4*)uvw)[idx] = ((const i32x4*)ws_s)[idx];
    }
    if (tid < 480)                        // w2f: 480 int4
        ((i32x4*)w2f)[tid] = ((const i32x4*)&ws_s[WS_W2F_OFF])[tid];
    {   // qt[b] = target[b] @ Wq[:64]  (fp32)
        int d = tid & 63, l0 = tid >> 6;
        for (int lb = l0; lb < NB; lb += NWAVE) {
            const float* trow = target + (size_t)(b0 + lb) * DD;
            float acc = 0.f;
            #pragma unroll 8
            for (int c = 0; c < DD; ++c) acc += trow[c] * Wq[c*DD + d];
            qtLDS[lb][d] = acc;
        }
    }

    const int i16 = lane & 15;
    const int g   = lane >> 4;
    const int dA  = 8 * g, dB = 32 + 8 * g;

    float b2v[3], w3v[3];
    #pragma unroll
    for (int t = 0; t < 3; ++t) {
        int c = i16 + 16*t;
        b2v[t] = (c < 40) ? b2[c] : 0.f;
        w3v[t] = (c < 40) ? W3[c] : 0.f;
    }
    const float b3v = b3[0];
    __syncthreads();

    // ---------------- phase 1: main loop ----------------
    f32x4 cur[4];
    {
        const float* srow0 = seq + (size_t)(wg*(NB*SS) + wv*16 + i16) * DD;
        #pragma unroll
        for (int c = 0; c < 4; ++c)
            cur[c] = *(const f32x4*)&srow0[(c < 2 ? dA : dB) + (c & 1)*4];
    }

    #pragma unroll 1
    for (int mt = wv; mt < MT; mt += NWAVE) {
        const int rloc = mt*16 + i16;
        const int lb   = rloc / 50;
        const int s    = rloc - lb*50;
        const float* qprow = qp + s*DD;

        // feat fragments (row = i16 = seq row, k = 8g+j per 32-step) — B side
        union { i32x4 w; bf16x8 h; } A[6];
        #pragma unroll
        for (int c = 0; c < 4; ++c) {
            const int d0 = (c < 2 ? dA : dB) + (c & 1) * 4;
            const int fi = c >> 1;
            f32x4 x  = *(const f32x4*)&qtLDS[lb][d0] + *(const f32x4*)&qprow[d0];
            f32x4 al = *(const f32x4*)&alpha[d0];
            f32x4 qv, pk;
            #pragma unroll
            for (int j = 0; j < 4; ++j) {
                float xx = x[j];
                qv[j] = xx >= 0.f ? xx : al[j]*xx;   // PReLU
                pk[j] = qv[j] * cur[c][j];           // q*k
            }
            const int wbase = (c & 1) * 2;
            A[0+fi].w[wbase]   = (int)f2bf2(qv[0], qv[1]);
            A[0+fi].w[wbase+1] = (int)f2bf2(qv[2], qv[3]);
            A[2+fi].w[wbase]   = (int)f2bf2(cur[c][0], cur[c][1]);
            A[2+fi].w[wbase+1] = (int)f2bf2(cur[c][2], cur[c][3]);
            A[4+fi].w[wbase]   = (int)f2bf2(pk[0], pk[1]);
            A[4+fi].w[wbase+1] = (int)f2bf2(pk[2], pk[3]);
        }

        // prefetch next tile's seq row (clamped)
        {
            const int mtn = (mt + NWAVE < MT) ? mt + NWAVE : mt;
            const float* srown = seq + (size_t)(wg*(NB*SS) + mtn*16 + i16) * DD;
            #pragma unroll
            for (int c = 0; c < 4; ++c)
                cur[c] = *(const f32x4*)&srown[(c < 2 ? dA : dB) + (c & 1)*4];
        }

        // GEMM1 SWAPPED: C = uvw^T-frag (A) x feat-frag (B) -> lane(c=i16,g)
        // holds pre1[seq-row i16][h=16t+4g+ii]; bias in C-init; sigmoid+pack
        bf16x4 a2[5];
        #pragma unroll
        for (int t = 0; t < 5; ++t) {
            f32x4 c = *(const f32x4*)&b1[16*t + 4*g];   // bias init (L1-hot)
            #pragma unroll
            for (int ks = 0; ks < 6; ++ks) {
                bf16x8 uf = *(const bf16x8*)&uvw[(t*6+ks)*512 + lane*8];
                c = __builtin_amdgcn_mfma_f32_16x16x32_bf16(uf, A[ks].h, c, 0, 0, 0);
            }
            union { uint32_t u[2]; bf16x4 s; } tmp;
            tmp.u[0] = f2bf2(fsig(c[0]), fsig(c[1]));
            tmp.u[1] = f2bf2(fsig(c[2]), fsig(c[3]));
            a2[t] = tmp.s;
        }

        // GEMM2: 16x16x16, K=80 = 5 steps, h1 straight from registers
        f32x4 acc2[3];
        #pragma unroll
        for (int t2 = 0; t2 < 3; ++t2) {
            acc2[t2] = (f32x4){b2v[t2], b2v[t2], b2v[t2], b2v[t2]};
            union { bf16x8 w; bf16x4 h[2]; } p01, p23;
            p01.w = *(const bf16x8*)&w2f[t2*1280 + lane*8];
            p23.w = *(const bf16x8*)&w2f[t2*1280 + 512 + lane*8];
            bf16x4 p4 = *(const bf16x4*)&w2f[t2*1280 + 1024 + lane*4];
            acc2[t2] = mfma16(a2[0], p01.h[0], acc2[t2]);
            acc2[t2] = mfma16(a2[1], p01.h[1], acc2[t2]);
            acc2[t2] = mfma16(a2[2], p23.h[0], acc2[t2]);
            acc2[t2] = mfma16(a2[3], p23.h[1], acc2[t2]);
            acc2[t2] = mfma16(a2[4], p4,       acc2[t2]);
        }
        mfma16_hazard_fence();

        // scores: rows 4g+ii (seq rows), reduce over feature lanes (i16)
        float sc[4];
        #pragma unroll
        for (int ii = 0; ii < 4; ++ii) {
            float v = 0.f;
            #pragma unroll
            for (int t = 0; t < 3; ++t)
                v += fsig(acc2[t][ii]) * w3v[t];
            sc[ii] = v;
        }
        #pragma unroll
        for (int off = 1; off < 16; off <<= 1)
            #pragma unroll
            for (int ii = 0; ii < 4; ++ii)
                sc[ii] += __shfl_xor(sc[ii], off, 64);
        if (i16 == 0) {
            #pragma unroll
            for (int ii = 0; ii < 4; ++ii) {
                int row = mt*16 + 4*g + ii;
                int lb2 = row / 50, s2 = row - lb2*50;
                scores[lb2][s2] = sc[ii] + b3v;
            }
        }
    }
    __syncthreads();

    // ---------------- phase 2: masked softmax + weighted sum ----------------
    for (int lb = wv*2; lb < wv*2 + 2; ++lb) {
        const int b = b0 + lb;
        float sval = 0.f; int mval = 0;
        if (lane < SS) { sval = scores[lb][lane]; mval = mask[b*SS + lane]; }
        float ms = (lane < SS) ? (mval != 0 ? sval : -1e9f) : -INFINITY;
        float M = ms;
        #pragma unroll
        for (int off = 1; off < 64; off <<= 1) M = fmaxf(M, __shfl_xor(M, off, 64));
        float e = fexp(ms - M);
        float Ssum = e;
        #pragma unroll
        for (int off = 1; off < 64; off <<= 1) Ssum += __shfl_xor(Ssum, off, 64);
        float p = e * __builtin_amdgcn_rcpf(Ssum);
        float rel = (lane < SS && mval != 0) ? sval : 0.f;
        #pragma unroll
        for (int off = 1; off < 64; off <<= 1) rel += __shfl_xor(rel, off, 64);
        if (lane < SS) scores[lb][lane] = p;
        asm volatile("s_waitcnt lgkmcnt(0)" ::: "memory");

        // PV vectorized: lane = sg(lane&3) x dq(lane>>2)
        const int sg = lane & 3, dq = lane >> 2;
        const float* sb = seq + (size_t)b * SS * DD + dq*4;
        f32x4 acc4 = {0.f,0.f,0.f,0.f};
        #pragma unroll
        for (int i = 0; i < 13; ++i) {
            int s = sg + 4*i;
            if (s < SS) {
                float pp = scores[lb][s];
                f32x4 v = *(const f32x4*)&sb[s*DD];
                acc4 += pp * v;
            }
        }
        #pragma unroll
        for (int off = 1; off < 4; off <<= 1)
            #pragma unroll
            for (int j = 0; j < 4; ++j)
                acc4[j] += __shfl_xor(acc4[j], off, 64);
        if (sg == 0) *(f32x4*)&out[(size_t)b * DD + dq*4] = acc4;
        if (lane == 0) out[(size_t)BB * DD + b] = rel;
    }
}

extern "C" void kernel_launch(void* const* d_in, const int* in_sizes, int n_in,
                              void* d_out, int out_size, void* d_ws, size_t ws_size,
                              hipStream_t stream) {
    const float* target = (const float*)d_in[0];
    const float* seq    = (const float*)d_in[1];
    const int*   mask   = (const int*)d_in[2];
    const float* pos    = (const float*)d_in[3];
    const float* Wq     = (const float*)d_in[4];
    const float* bq     = (const float*)d_in[5];
    const float* alpha  = (const float*)d_in[6];
    const float* W1     = (const float*)d_in[7];
    const float* b1     = (const float*)d_in[8];
    const float* W2     = (const float*)d_in[9];
    const float* b2     = (const float*)d_in[10];
    const float* W3     = (const float*)d_in[11];
    const float* b3     = (const float*)d_in[12];
    float* outp = (float*)d_out;

    short* ws_s = (short*)d_ws;
    float* qp   = (float*)((char*)d_ws + WS_QP_BYTE_OFF);

    hipLaunchKernelGGL(i2i_prep, dim3(24), dim3(256), 0, stream,
                       pos, Wq, bq, W1, W2, ws_s, qp);
    hipLaunchKernelGGL(i2i_kernel, dim3(BB / NB), dim3(512), 0, stream,
                       target, seq, mask, Wq, alpha, b1, b2, W3, b3, ws_s, qp, outp);
}